// Round 9
// baseline (374.765 us; speedup 1.0000x reference)
//
#include <hip/hip_runtime.h>
#include <math.h>

// DiffDispatchLP: batched (256x) PDHG, 400 iters. ONE WAVE PER ITEM.
// Lane l owns t = 2l, 2l+1 (lanes 48-63 are zero-lanes). All primal/dual
// state in registers; all cross-t coupling (reach <= 3) via ds_bpermute
// (wraparound hits zero-lanes => no boundary reads); total-charge row via
// butterfly reduce. No LDS arrays, no __syncthreads, no loop memory ops.

#define NITER 400
#define PITER 10

__device__ __forceinline__ float bperm(int addr, float v) {
  return __int_as_float(__builtin_amdgcn_ds_bpermute(addr, __float_as_int(v)));
}
__device__ __forceinline__ float xorsum(float v) {
#pragma unroll
  for (int m = 32; m >= 1; m >>= 1) v += __shfl_xor(v, m, 64);
  return v;
}

__global__ __launch_bounds__(64, 1)
void lp_solve_kernel(const float* __restrict__ price, float* __restrict__ out) {
  const int lane = threadIdx.x, bi = blockIdx.x;
  const double ETA_D = sqrt(0.91);
  const float cET = (float)(-(ETA_D * 0.25));  // -ETA*DT
  const float cDE = (float)(0.25 / ETA_D);     // DT/ETA

  const bool act = lane < 48;
  const float actf = act ? 1.f : 0.f;
  // row-validity masks (include act). te=2l, to=2l+1.
  const float mRe = (act && lane >= 1) ? 1.f : 0.f;   // ramp row te>=1
  const float mRo = actf;                              // to>=1 always
  const float mSe = actf;                              // sw row te<=94 always
  const float mSo = (act && lane <= 46) ? 1.f : 0.f;   // to<=94
  const float mM1e = actf, mM1o = mSo;                 // md k=1: t<=94
  const float mM2  = (act && lane <= 46) ? 1.f : 0.f;  // t<=93 (e&o) and te<=92
  const float mM3o = (act && lane <= 45) ? 1.f : 0.f;  // to<=92
  const float m96 = (lane == 47) ? 1.f : 0.f;

  const int aU1 = ((lane - 1) & 63) << 2;
  const int aU2 = ((lane - 2) & 63) << 2;
  const int aD1 = ((lane + 1) & 63) << 2;
  const int aD2 = ((lane + 2) & 63) << 2;

  // ---- dual state (registers) ----
  float B0e,B1e,B2e,B3e,B4e,B5e,B6e,B7e,B8e,B9e,B10e,B11e,B12e;
  float B0o,B1o,B2o,B3o,B4o,B5o,B6o,B7o,B8o,B9o,B10o,B11o,B12o;
  float A1e,A2e,A3e,A1o,A2o,A3o;   // min-dur yc (k=1..3)
  float C1e,C2e,C3e,C1o,C2o,C3o;   // min-dur yd
  float R0e,R1e,R2e,R3e,R0o,R1o,R2o,R3o;  // ramp c-up,c-dn,d-up,d-dn
  float P0e,P1e,P0o,P1o;           // switch
  float Ee,Eo,E96,Ytc;             // equality, eq row 96, total-charge
  // ---- primal ----
  float xce,xco,xde,xdo,xyce,xyco,xyde,xydo,xse,xso;       // x
  float bce,bco,bde,bdo,byce,byco,byde,bydo,bse,bso;       // x_bar (or power v)
  float gce,gco,gde,gdo,gyce,gyco,gyde,gydo,gse,gso;       // K^T y per column
  float sigv = 0.f;

  auto zeroDuals = [&]() {
    B0e=B1e=B2e=B3e=B4e=B5e=B6e=B7e=B8e=B9e=B10e=B11e=B12e=0.f;
    B0o=B1o=B2o=B3o=B4o=B5o=B6o=B7o=B8o=B9o=B10o=B11o=B12o=0.f;
    A1e=A2e=A3e=A1o=A2o=A3o=0.f; C1e=C2e=C3e=C1o=C2o=C3o=0.f;
    R0e=R1e=R2e=R3e=R0o=R1o=R2o=R3o=0.f;
    P0e=P1e=P0o=P1o=0.f; Ee=Eo=E96=Ytc=0.f;
  };

  // phase A: g = (K^T y)[col] for my 10 columns
  auto gatherAll = [&]() {
    float msAe = A1e+A2e+A3e, msAo = A1o+A2o+A3o;   // min-dur own-sums
    float msBe = C1e+C2e+C3e, msBo = C1o+C2o+C3o;
    float uce = R0e-R1e, uco = R0o-R1o;             // ramp combos
    float ude = R2e-R3e, udo = R2o-R3o;
    float ucD  = bperm(aD1, uce);    // uc[t+1] for odd slice
    float udD  = bperm(aD1, ude);
    float msAD = bperm(aD1, msAe);   // MS[t+1] for odd
    float msBD = bperm(aD1, msBe);
    float eqD  = bperm(aD1, Ee);     // eq[t+1] for odd
    float A1U  = bperm(aU1, A1o);    // MD1[t-1] for even
    float C1U  = bperm(aU1, C1o);
    float A2Ue = bperm(aU1, A2e);    // MD2[t-2]
    float A2Uo = bperm(aU1, A2o);
    float C2Ue = bperm(aU1, C2e);
    float C2Uo = bperm(aU1, C2o);
    float A3Ue = bperm(aU2, A3o);    // MD3[t-3]
    float A3Uo = bperm(aU1, A3e);
    float C3Ue = bperm(aU2, C3o);
    float C3Uo = bperm(aU1, C3e);
    float P1U  = bperm(aU1, P1o);    // sw1[t-1] for even
    float P0U  = bperm(aU1, P0o);    // sw0[t-1] for even
    gce = actf*((B0e - B2e + B11e) + cET*Ee + uce - uco + 0.25f*Ytc);
    gco = actf*((B0o - B2o + B11o) + cET*Eo + uco - ucD + 0.25f*Ytc);
    gde = actf*((B1e - B3e + B12e) + cDE*Ee + ude - udo);
    gdo = actf*((B1o - B3o + B12o) + cDE*Eo + udo - udD);
    gyce = actf*((-B4e + B5e + B10e - 195.f*B11e) + P0e + P1U
                 + msAe - msAo - (A1U + A2Ue + A3Ue));
    gyco = actf*((-B4o + B5o + B10o - 195.f*B11o) + P0o + P1e
                 + msAo - msAD - (A1e + A2Uo + A3Uo));
    gyde = actf*((-B6e + B7e + B10e - 195.f*B12e) + P1e + P0U
                 + msBe - msBo - (C1U + C2Ue + C3Ue));
    gydo = actf*((-B6o + B7o + B10o - 195.f*B12o) + P1o + P0e
                 + msBo - msBD - (C1e + C2Uo + C3Uo));
    gse = actf*((-B8e + B9e) + Ee - Eo);
    gso = actf*((-B8o + B9o) + Eo - eqD + m96*E96);
  };

  // phase B: dual update (or raw dots in power mode) from x_bar
  auto phaseB = [&](bool power) {
    const float sig = sigv;
    float sU    = bperm(aU1, bso);    // s_bar[t-1] for even
    float cU    = bperm(aU1, bco);    // c_bar[t-1]
    float dU    = bperm(aU1, bdo);
    float ycU   = bperm(aU1, byco);   // y_bar[t-1]
    float ydU   = bperm(aU1, bydo);
    float ycD1e = bperm(aD1, byce);   // yc_bar at te+2 / to+1
    float ydD1e = bperm(aD1, byde);
    float ycD1o = bperm(aD1, byco);   // at te+3 / to+2
    float ydD1o = bperm(aD1, bydo);
    float ycD2  = bperm(aD2, byce);   // at to+3
    float ydD2  = bperm(aD2, byde);
    // BOX (13 rows per t)
    if (power) {
      B0e=actf*bce; B1e=actf*bde; B2e=-actf*bce; B3e=-actf*bde;
      B4e=-actf*byce; B5e=actf*byce; B6e=-actf*byde; B7e=actf*byde;
      B8e=-actf*bse; B9e=actf*bse; B10e=actf*(byce+byde);
      B11e=actf*(bce-195.f*byce); B12e=actf*(bde-195.f*byde);
      B0o=actf*bco; B1o=actf*bdo; B2o=-actf*bco; B3o=-actf*bdo;
      B4o=-actf*byco; B5o=actf*byco; B6o=-actf*bydo; B7o=actf*bydo;
      B8o=-actf*bso; B9o=actf*bso; B10o=actf*(byco+bydo);
      B11o=actf*(bco-195.f*byco); B12o=actf*(bdo-195.f*bydo);
    } else {
      B0e=actf*fmaxf(B0e+sig*(bce-195.f),0.f);  B0o=actf*fmaxf(B0o+sig*(bco-195.f),0.f);
      B1e=actf*fmaxf(B1e+sig*(bde-195.f),0.f);  B1o=actf*fmaxf(B1o+sig*(bdo-195.f),0.f);
      B2e=actf*fmaxf(B2e-sig*bce,0.f);          B2o=actf*fmaxf(B2o-sig*bco,0.f);
      B3e=actf*fmaxf(B3e-sig*bde,0.f);          B3o=actf*fmaxf(B3o-sig*bdo,0.f);
      B4e=actf*fmaxf(B4e-sig*byce,0.f);         B4o=actf*fmaxf(B4o-sig*byco,0.f);
      B5e=actf*fmaxf(B5e+sig*(byce-1.f),0.f);   B5o=actf*fmaxf(B5o+sig*(byco-1.f),0.f);
      B6e=actf*fmaxf(B6e-sig*byde,0.f);         B6o=actf*fmaxf(B6o-sig*bydo,0.f);
      B7e=actf*fmaxf(B7e+sig*(byde-1.f),0.f);   B7o=actf*fmaxf(B7o+sig*(bydo-1.f),0.f);
      B8e=actf*fmaxf(B8e-sig*bse,0.f);          B8o=actf*fmaxf(B8o-sig*bso,0.f);
      B9e=actf*fmaxf(B9e+sig*(bse-800.f),0.f);  B9o=actf*fmaxf(B9o+sig*(bso-800.f),0.f);
      B10e=actf*fmaxf(B10e+sig*(byce+byde-1.f),0.f);
      B10o=actf*fmaxf(B10o+sig*(byco+bydo-1.f),0.f);
      B11e=actf*fmaxf(B11e+sig*(bce-195.f*byce),0.f);
      B11o=actf*fmaxf(B11o+sig*(bco-195.f*byco),0.f);
      B12e=actf*fmaxf(B12e+sig*(bde-195.f*byde),0.f);
      B12o=actf*fmaxf(B12o+sig*(bdo-195.f*bydo),0.f);
    }
    // MIN-DURATION yc
    {
      float base_e = byce - ycU, base_o = byco - byce;
      float d1e = base_e - byco,  d2e = base_e - ycD1e, d3e = base_e - ycD1o;
      float d1o = base_o - ycD1e, d2o = base_o - ycD1o, d3o = base_o - ycD2;
      if (power) {
        A1e=mM1e*d1e; A2e=mM2*d2e; A3e=mM2*d3e;
        A1o=mM1o*d1o; A2o=mM2*d2o; A3o=mM3o*d3o;
      } else {
        A1e=mM1e*fmaxf(A1e+sig*d1e,0.f); A2e=mM2*fmaxf(A2e+sig*d2e,0.f);
        A3e=mM2*fmaxf(A3e+sig*d3e,0.f);  A1o=mM1o*fmaxf(A1o+sig*d1o,0.f);
        A2o=mM2*fmaxf(A2o+sig*d2o,0.f);  A3o=mM3o*fmaxf(A3o+sig*d3o,0.f);
      }
    }
    // MIN-DURATION yd
    {
      float base_e = byde - ydU, base_o = bydo - byde;
      float d1e = base_e - bydo,  d2e = base_e - ydD1e, d3e = base_e - ydD1o;
      float d1o = base_o - ydD1e, d2o = base_o - ydD1o, d3o = base_o - ydD2;
      if (power) {
        C1e=mM1e*d1e; C2e=mM2*d2e; C3e=mM2*d3e;
        C1o=mM1o*d1o; C2o=mM2*d2o; C3o=mM3o*d3o;
      } else {
        C1e=mM1e*fmaxf(C1e+sig*d1e,0.f); C2e=mM2*fmaxf(C2e+sig*d2e,0.f);
        C3e=mM2*fmaxf(C3e+sig*d3e,0.f);  C1o=mM1o*fmaxf(C1o+sig*d1o,0.f);
        C2o=mM2*fmaxf(C2o+sig*d2o,0.f);  C3o=mM3o*fmaxf(C3o+sig*d3o,0.f);
      }
    }
    // RAMP (rows at t: c/d up/down)
    {
      float rce = bce - cU, rco = bco - bce;
      float rde = bde - dU, rdo = bdo - bde;
      if (power) {
        R0e=mRe*rce; R1e=-mRe*rce; R2e=mRe*rde; R3e=-mRe*rde;
        R0o=mRo*rco; R1o=-mRo*rco; R2o=mRo*rdo; R3o=-mRo*rdo;
      } else {
        R0e=mRe*fmaxf(R0e+sig*(rce-65.f),0.f); R1e=mRe*fmaxf(R1e+sig*(-rce-65.f),0.f);
        R2e=mRe*fmaxf(R2e+sig*(rde-65.f),0.f); R3e=mRe*fmaxf(R3e+sig*(-rde-65.f),0.f);
        R0o=mRo*fmaxf(R0o+sig*(rco-65.f),0.f); R1o=mRo*fmaxf(R1o+sig*(-rco-65.f),0.f);
        R2o=mRo*fmaxf(R2o+sig*(rdo-65.f),0.f); R3o=mRo*fmaxf(R3o+sig*(-rdo-65.f),0.f);
      }
    }
    // SWITCH (2 rows at t)
    {
      float s0e = byce + bydo, s1e = byde + byco;
      float s0o = byco + ydD1e, s1o = bydo + ycD1e;
      if (power) { P0e=mSe*s0e; P1e=mSe*s1e; P0o=mSo*s0o; P1o=mSo*s1o; }
      else {
        P0e=mSe*fmaxf(P0e+sig*(s0e-1.f),0.f); P1e=mSe*fmaxf(P1e+sig*(s1e-1.f),0.f);
        P0o=mSo*fmaxf(P0o+sig*(s0o-1.f),0.f); P1o=mSo*fmaxf(P1o+sig*(s1o-1.f),0.f);
      }
    }
    // EQUALITY (free duals) + row 96
    {
      float de_ = bse - sU + cET*bce + cDE*bde;
      float do_ = bso - bse + cET*bco + cDE*bdo;
      if (power) { Ee=actf*de_; Eo=actf*do_; E96=m96*bso; }
      else { Ee=actf*(Ee+sig*de_); Eo=actf*(Eo+sig*do_); E96=m96*(E96+sig*bso); }
    }
    // TOTAL-CHARGE: 0.25*sum(c_bar) <= 1200 (uniform across lanes)
    {
      float sc = xorsum(bce + bco);
      float tdot = 0.25f*sc;
      Ytc = power ? tdot : fmaxf(Ytc + sigv*(tdot - 1200.f), 0.f);
    }
  };

  // ================= power iteration: ||K||_2 =================
  zeroDuals();
  bce=bco=bde=bdo=byce=byco=byde=bydo=bse=bso=actf;
  float lam2 = 1.f;
#pragma unroll 1
  for (int pit = 0; pit < PITER; ++pit) {
    phaseB(true);
    gatherAll();
    float part = gce*gce+gco*gco+gde*gde+gdo*gdo+gyce*gyce
               + gyco*gyco+gyde*gyde+gydo*gydo+gse*gse+gso*gso;
    part = xorsum(part);
    lam2 = sqrtf(part);
    float inv = 1.f / lam2;
    bce=gce*inv; bco=gco*inv; bde=gde*inv; bdo=gdo*inv;
    byce=gyce*inv; byco=gyco*inv; byde=gyde*inv; bydo=gydo*inv;
    bse=gse*inv; bso=gso*inv;
  }
  const float tauv = (float)(0.9 / sqrt((double)lam2));
  sigv = tauv;

  // ================= PDHG =================
  zeroDuals();
  xce=xco=xde=xdo=xyce=xyco=xyde=xydo=xse=xso=0.f;
  bce=bco=bde=bdo=byce=byco=byde=bydo=bse=bso=0.f;
  const int pidx = bi*96 + 2*((lane < 48) ? lane : 47);
  float2 pv = *(const float2*)(price + pidx);
  float qce = actf*0.25f*pv.x, qco = actf*0.25f*pv.y;
  float qde = -qce, qdo = -qco;

#pragma unroll 1
  for (int it = 0; it < NITER; ++it) {
    gatherAll();
    float xn;
    xn = xce - tauv*(qce+gce); bce = 2.f*xn - xce; xce = xn;
    xn = xco - tauv*(qco+gco); bco = 2.f*xn - xco; xco = xn;
    xn = xde - tauv*(qde+gde); bde = 2.f*xn - xde; xde = xn;
    xn = xdo - tauv*(qdo+gdo); bdo = 2.f*xn - xdo; xdo = xn;
    xn = xyce - tauv*gyce; byce = 2.f*xn - xyce; xyce = xn;
    xn = xyco - tauv*gyco; byco = 2.f*xn - xyco; xyco = xn;
    xn = xyde - tauv*gyde; byde = 2.f*xn - xyde; xyde = xn;
    xn = xydo - tauv*gydo; bydo = 2.f*xn - xydo; xydo = xn;
    xn = xse - tauv*gse; bse = 2.f*xn - xse; xse = xn;
    xn = xso - tauv*gso; bso = 2.f*xn - xso; xso = xn;
    phaseB(false);
  }

  // output: c then d, each (256,96)
  if (act) {
    float2 rc; rc.x = xce; rc.y = xco;
    float2 rd; rd.x = xde; rd.y = xdo;
    *(float2*)(out + bi*96 + 2*lane) = rc;
    *(float2*)(out + 24576 + bi*96 + 2*lane) = rd;
  }
}

extern "C" void kernel_launch(void* const* d_in, const int* in_sizes, int n_in,
                              void* d_out, int out_size, void* d_ws, size_t ws_size,
                              hipStream_t stream) {
  const float* price = (const float*)d_in[0];
  float* outp = (float*)d_out;
  hipLaunchKernelGGL(lp_solve_kernel, dim3(256), dim3(64), 0, stream, price, outp);
}